// Round 4
// baseline (763.875 us; speedup 1.0000x reference)
//
#include <hip/hip_runtime.h>
#include <math.h>

#define D 128

__device__ __forceinline__ float sigmoidf_(float x) { return 1.f / (1.f + __expf(-x)); }

// ---------------- segment bounds: seg_off[g] = lower_bound(index, g) ----------------
__global__ void seg_bounds_kernel(const int* __restrict__ idx, int N, int G,
                                  int* __restrict__ seg_off) {
    int g = blockIdx.x * blockDim.x + threadIdx.x;
    if (g > G) return;
    int lo = 0, hi = N;
    while (lo < hi) {
        int mid = (lo + hi) >> 1;
        if (idx[mid] < g) lo = mid + 1; else hi = mid;
    }
    seg_off[g] = lo;
}

// ---------------- Wc = W_ih[:, :D] + W_hh  ([512, D] row-major) --------
__global__ void prep_wc_kernel(const float* __restrict__ W_ih, const float* __restrict__ W_hh,
                               float* __restrict__ Wc) {
    int t = blockIdx.x * blockDim.x + threadIdx.x;
    if (t >= 4 * D * D) return;
    int j = t >> 7;
    int k = t & (D - 1);
    Wc[t] = W_ih[(size_t)j * (2 * D) + k] + W_hh[t];
}

// ---------------- b_sum = b_ih + b_hh; h1/c1 from biases only ----------------
__global__ void prep_bias_kernel(const float* __restrict__ b_ih, const float* __restrict__ b_hh,
                                 float* __restrict__ b_sum, float* __restrict__ h1,
                                 float* __restrict__ c1) {
    int t = threadIdx.x;  // 512 threads, 1 block
    float b = b_ih[t] + b_hh[t];
    b_sum[t] = b;
    if (t < D) {
        float bi = b_ih[t] + b_hh[t];
        float bg = b_ih[2 * D + t] + b_hh[2 * D + t];
        float bo = b_ih[3 * D + t] + b_hh[3 * D + t];
        float c = sigmoidf_(bi) * tanhf(bg);
        c1[t] = c;
        h1[t] = sigmoidf_(bo) * tanhf(c);
    }
}

// ---------------- base2[j] = b_sum[j] + dot(h1, Wc[j,:]) ----------------
__global__ void base2_kernel(const float* __restrict__ Wc, const float* __restrict__ b_sum,
                             const float* __restrict__ h1, float* __restrict__ base2) {
    __shared__ float hs[D];
    int j = blockIdx.x * 256 + threadIdx.x;
    if (threadIdx.x < D) hs[threadIdx.x] = h1[threadIdx.x];
    __syncthreads();
    float acc = 0.f;
    const float4* w4 = (const float4*)(Wc + (size_t)j * D);
#pragma unroll 8
    for (int k4 = 0; k4 < D / 4; ++k4) {
        float4 w = w4[k4];
        const float* hp = &hs[k4 * 4];
        acc += w.x * hp[0] + w.y * hp[1] + w.z * hp[2] + w.w * hp[3];
    }
    base2[j] = b_sum[j] + acc;
}

// ---------------- pass 1: scores e[n] = dot(x[n], q[seg(n)]) ----------------
// One block per segment, 4 waves split rows. Per wave: lanes 0-31 row n, 32-63 row n+1,
// float4/lane. 4-deep prefetch pipeline; 5-shuffle butterfly per pair; no serial coupling.
__global__ __launch_bounds__(256) void score_kernel(
    const float* __restrict__ x, const int* __restrict__ seg_off,
    const float* __restrict__ q, int q_stride,
    float* __restrict__ e, int G) {
    int g = blockIdx.x;
    if (g >= G) return;
    int tid = threadIdx.x;
    int wave = tid >> 6, lane = tid & 63;
    int half = lane >> 5, col4 = lane & 31;

    int start = seg_off[g], end = seg_off[g + 1];
    int count = end - start;
    int chunk = (count + 3) >> 2;
    int wsr = start + wave * chunk;
    int wer = min(wsr + chunk, end);
    if (wsr >= wer) return;

    const float4* x4 = (const float4*)x;
    const float4* q4 = (const float4*)(q + (size_t)g * q_stride);
    float4 qv = q4[col4];

    int np = (wer - wsr + 1) >> 1;   // pairs (last may be a singleton)
    float4 buf[4];
#pragma unroll
    for (int j = 0; j < 4; ++j) {
        int ip = j < np ? j : np - 1;
        int row = wsr + 2 * ip + half; row = row < wer ? row : wer - 1;
        buf[j] = x4[(size_t)row * 32 + col4];
    }
    for (int i = 0; i < np; ++i) {
        float4 xv = buf[i & 3];
        int ip = i + 4; ip = ip < np ? ip : np - 1;
        int rowp = wsr + 2 * ip + half; rowp = rowp < wer ? rowp : wer - 1;
        buf[i & 3] = x4[(size_t)rowp * 32 + col4];

        float p = xv.x * qv.x + xv.y * qv.y + xv.z * qv.z + xv.w * qv.w;
        p += __shfl_xor(p, 1);
        p += __shfl_xor(p, 2);
        p += __shfl_xor(p, 4);
        p += __shfl_xor(p, 8);
        p += __shfl_xor(p, 16);
        int rs = wsr + 2 * i + half;
        if (col4 == 0 && rs < wer) e[rs] = p;
    }
}

// ---------------- pass 2: segment stats (m, s) + weighted sum ----------------
// Stats over L2-hot e; then streaming acc += exp(e-m)*inv * x with 4-deep prefetch.
__global__ __launch_bounds__(256) void wsum_kernel(
    const float* __restrict__ x, const int* __restrict__ seg_off,
    const float* __restrict__ e,
    float* __restrict__ r_out, int r_stride, int G) {
    int g = blockIdx.x;
    if (g >= G) return;
    int tid = threadIdx.x;
    int wave = tid >> 6, lane = tid & 63;
    int half = lane >> 5, col4 = lane & 31;

    __shared__ float sred[4];
    __shared__ float sacc[4][D];

    int start = seg_off[g], end = seg_off[g + 1];

    // --- segment max ---
    float lm = -INFINITY;
    for (int i = start + tid; i < end; i += 256) lm = fmaxf(lm, e[i]);
#pragma unroll
    for (int off = 1; off < 64; off <<= 1) lm = fmaxf(lm, __shfl_xor(lm, off));
    if (lane == 0) sred[wave] = lm;
    __syncthreads();
    float m = fmaxf(fmaxf(sred[0], sred[1]), fmaxf(sred[2], sred[3]));
    __syncthreads();
    // --- segment sum of exp(e - m) ---
    float ls = 0.f;
    for (int i = start + tid; i < end; i += 256) ls += __expf(e[i] - m);
#pragma unroll
    for (int off = 1; off < 64; off <<= 1) ls += __shfl_xor(ls, off);
    if (lane == 0) sred[wave] = ls;
    __syncthreads();
    float s = sred[0] + sred[1] + sred[2] + sred[3];
    float inv = 1.f / fmaxf(s, 1e-16f);

    // --- streaming weighted sum ---
    int count = end - start;
    int chunk = (count + 3) >> 2;
    int wsr = start + wave * chunk;
    int wer = min(wsr + chunk, end);

    const float4* x4 = (const float4*)x;
    float4 acc = {0.f, 0.f, 0.f, 0.f};

    if (wsr < wer) {
        int np = (wer - wsr + 1) >> 1;
        float4 xb[4]; float eb[4];
#pragma unroll
        for (int j = 0; j < 4; ++j) {
            int ip = j < np ? j : np - 1;
            int row = wsr + 2 * ip + half; row = row < wer ? row : wer - 1;
            xb[j] = x4[(size_t)row * 32 + col4];
            eb[j] = e[row];
        }
        for (int i = 0; i < np; ++i) {
            float4 xv = xb[i & 3];
            float ev = eb[i & 3];
            int ip = i + 4; ip = ip < np ? ip : np - 1;
            int rowp = wsr + 2 * ip + half; rowp = rowp < wer ? rowp : wer - 1;
            xb[i & 3] = x4[(size_t)rowp * 32 + col4];
            eb[i & 3] = e[rowp];

            int rs = wsr + 2 * i + half;
            float w = (rs < wer) ? __expf(ev - m) * inv : 0.f;
            acc.x += w * xv.x;
            acc.y += w * xv.y;
            acc.z += w * xv.z;
            acc.w += w * xv.w;
        }
    }
    // merge halves, then 4 waves via LDS (plain adds — weights globally normalized)
    acc.x += __shfl_xor(acc.x, 32);
    acc.y += __shfl_xor(acc.y, 32);
    acc.z += __shfl_xor(acc.z, 32);
    acc.w += __shfl_xor(acc.w, 32);
    if (half == 0) *(float4*)&sacc[wave][col4 * 4] = acc;
    __syncthreads();
    if (tid < D) {
        float r = sacc[0][tid] + sacc[1][tid] + sacc[2][tid] + sacc[3][tid];
        r_out[(size_t)g * r_stride + tid] = r;
    }
}

// ---------------- gates GEMM (unchanged) ----------------
__global__ __launch_bounds__(256) void gates_gemm_kernel(
    const float* __restrict__ A1, const float* __restrict__ W1,
    const float* __restrict__ A2, const float* __restrict__ W2, int sW2,
    const float* __restrict__ bias, float* __restrict__ gates) {
    __shared__ float As[16][132];
    __shared__ float Ws[16][132];
    int t = threadIdx.x;
    int tx = t & 15, ty = t >> 4;
    int g0 = blockIdx.x * 128, j0 = blockIdx.y * 128;
    int lr = t >> 1;
    int lk = (t & 1) * 8;

    float acc[8][8];
#pragma unroll
    for (int i = 0; i < 8; ++i)
#pragma unroll
        for (int j = 0; j < 8; ++j) acc[i][j] = 0.f;

    for (int phase = 0; phase < 2; ++phase) {
        const float* A = phase ? A2 : A1;
        if (A == nullptr) continue;
        const float* W = phase ? W2 : W1;
        int sW = phase ? sW2 : D;
        for (int kk = 0; kk < D; kk += 16) {
            float4 a0 = *(const float4*)&A[(size_t)(g0 + lr) * D + kk + lk];
            float4 a1 = *(const float4*)&A[(size_t)(g0 + lr) * D + kk + lk + 4];
            float4 w0 = *(const float4*)&W[(size_t)(j0 + lr) * sW + kk + lk];
            float4 w1 = *(const float4*)&W[(size_t)(j0 + lr) * sW + kk + lk + 4];
            __syncthreads();
            As[lk + 0][lr] = a0.x; As[lk + 1][lr] = a0.y; As[lk + 2][lr] = a0.z; As[lk + 3][lr] = a0.w;
            As[lk + 4][lr] = a1.x; As[lk + 5][lr] = a1.y; As[lk + 6][lr] = a1.z; As[lk + 7][lr] = a1.w;
            Ws[lk + 0][lr] = w0.x; Ws[lk + 1][lr] = w0.y; Ws[lk + 2][lr] = w0.z; Ws[lk + 3][lr] = w0.w;
            Ws[lk + 4][lr] = w1.x; Ws[lk + 5][lr] = w1.y; Ws[lk + 6][lr] = w1.z; Ws[lk + 7][lr] = w1.w;
            __syncthreads();
#pragma unroll
            for (int k = 0; k < 16; ++k) {
                float4 a0v = *(const float4*)&As[k][ty * 8];
                float4 a1v = *(const float4*)&As[k][ty * 8 + 4];
                float4 b0v = *(const float4*)&Ws[k][tx * 8];
                float4 b1v = *(const float4*)&Ws[k][tx * 8 + 4];
                float av[8] = {a0v.x, a0v.y, a0v.z, a0v.w, a1v.x, a1v.y, a1v.z, a1v.w};
                float bv[8] = {b0v.x, b0v.y, b0v.z, b0v.w, b1v.x, b1v.y, b1v.z, b1v.w};
#pragma unroll
                for (int i = 0; i < 8; ++i)
#pragma unroll
                    for (int j = 0; j < 8; ++j)
                        acc[i][j] = fmaf(av[i], bv[j], acc[i][j]);
            }
        }
    }
#pragma unroll
    for (int i = 0; i < 8; ++i) {
        size_t row = (size_t)(g0 + ty * 8 + i);
        float4 o0, o1;
        int jb = j0 + tx * 8;
        o0.x = acc[i][0] + bias[jb + 0]; o0.y = acc[i][1] + bias[jb + 1];
        o0.z = acc[i][2] + bias[jb + 2]; o0.w = acc[i][3] + bias[jb + 3];
        o1.x = acc[i][4] + bias[jb + 4]; o1.y = acc[i][5] + bias[jb + 5];
        o1.z = acc[i][6] + bias[jb + 6]; o1.w = acc[i][7] + bias[jb + 7];
        *(float4*)&gates[row * 512 + jb] = o0;
        *(float4*)&gates[row * 512 + jb + 4] = o1;
    }
}

// ---------------- LSTM cell elementwise ----------------
__global__ void cell_kernel(const float* __restrict__ gates,
                            const float* __restrict__ c_prev, int c_stride,
                            float* __restrict__ c_out,
                            float* __restrict__ h_out, int h_stride,
                            int total) {
    int t = blockIdx.x * blockDim.x + threadIdx.x;
    if (t >= total) return;
    int g = t >> 7, k = t & (D - 1);
    const float* grow = gates + (size_t)g * 512;
    float ig = grow[k];
    float fg = grow[D + k];
    float gg = grow[2 * D + k];
    float og = grow[3 * D + k];
    float cp = c_prev[(size_t)g * c_stride + k];
    float c = sigmoidf_(fg) * cp + sigmoidf_(ig) * tanhf(gg);
    float h = sigmoidf_(og) * tanhf(c);
    c_out[t] = c;
    h_out[(size_t)g * h_stride + k] = h;
}

extern "C" void kernel_launch(void* const* d_in, const int* in_sizes, int n_in,
                              void* d_out, int out_size, void* d_ws, size_t ws_size,
                              hipStream_t stream) {
    const float* x      = (const float*)d_in[0];
    const float* W_ih   = (const float*)d_in[1];
    const float* W_hh   = (const float*)d_in[2];
    const float* b_ih   = (const float*)d_in[3];
    const float* b_hh   = (const float*)d_in[4];
    const int*   index  = (const int*)d_in[5];
    int N = in_sizes[5];
    int G = out_size / (2 * D);
    float* out = (float*)d_out;

    float* ws = (float*)d_ws;
    float* Wc     = ws;                         // 512*D
    float* b_sum  = Wc + 4 * D * D;             // 512
    float* h1     = b_sum + 4 * D;              // D
    float* c1     = h1 + D;                     // D
    float* base2  = c1 + D;                     // 512
    float* r1     = base2 + 4 * D;              // G*D
    float* h2     = r1 + (size_t)G * D;         // G*D
    float* c2     = h2 + (size_t)G * D;         // G*D
    float* r2     = c2 + (size_t)G * D;         // G*D
    float* gatesb = r2 + (size_t)G * D;         // G*4D
    float* e_buf  = gatesb + (size_t)G * 4 * D; // N
    int* seg_off  = (int*)(e_buf + (size_t)N);  // G+1
    float* c3     = r1;  // r1 dead after step-3 GEMM; c3 never read

    seg_bounds_kernel<<<(G + 1 + 255) / 256, 256, 0, stream>>>(index, N, G, seg_off);
    prep_wc_kernel<<<(4 * D * D + 255) / 256, 256, 0, stream>>>(W_ih, W_hh, Wc);
    prep_bias_kernel<<<1, 512, 0, stream>>>(b_ih, b_hh, b_sum, h1, c1);
    base2_kernel<<<2, 256, 0, stream>>>(Wc, b_sum, h1, base2);

    // ---- step 1: q = h1 (broadcast)
    score_kernel<<<G, 256, 0, stream>>>(x, seg_off, h1, 0, e_buf, G);
    wsum_kernel<<<G, 256, 0, stream>>>(x, seg_off, e_buf, r1, D, G);

    // ---- step 2
    gates_gemm_kernel<<<dim3(G / 128, 4), 256, 0, stream>>>(
        nullptr, Wc, r1, W_ih + D, 2 * D, base2, gatesb);
    cell_kernel<<<(G * D + 255) / 256, 256, 0, stream>>>(gatesb, c1, 0, c2, h2, D, G * D);
    score_kernel<<<G, 256, 0, stream>>>(x, seg_off, h2, D, e_buf, G);
    wsum_kernel<<<G, 256, 0, stream>>>(x, seg_off, e_buf, r2, D, G);

    // ---- step 3
    gates_gemm_kernel<<<dim3(G / 128, 4), 256, 0, stream>>>(
        h2, Wc, r2, W_ih + D, 2 * D, b_sum, gatesb);
    cell_kernel<<<(G * D + 255) / 256, 256, 0, stream>>>(gatesb, c2, D, c3, out, 2 * D, G * D);
    score_kernel<<<G, 256, 0, stream>>>(x, seg_off, out, 2 * D, e_buf, G);
    wsum_kernel<<<G, 256, 0, stream>>>(x, seg_off, e_buf, out + D, 2 * D, G);
}

// Round 5
// 523.149 us; speedup vs baseline: 1.4601x; 1.4601x over previous
//
#include <hip/hip_runtime.h>
#include <math.h>

#define D 128

__device__ __forceinline__ float sigmoidf_(float x) { return 1.f / (1.f + __expf(-x)); }

// ---------------- segment bounds: seg_off[g] = lower_bound(index, g) ----------------
__global__ void seg_bounds_kernel(const int* __restrict__ idx, int N, int G,
                                  int* __restrict__ seg_off) {
    int g = blockIdx.x * blockDim.x + threadIdx.x;
    if (g > G) return;
    int lo = 0, hi = N;
    while (lo < hi) {
        int mid = (lo + hi) >> 1;
        if (idx[mid] < g) lo = mid + 1; else hi = mid;
    }
    seg_off[g] = lo;
}

// ---------------- Wc = W_ih[:, :D] + W_hh  ([512, D] row-major) --------
__global__ void prep_wc_kernel(const float* __restrict__ W_ih, const float* __restrict__ W_hh,
                               float* __restrict__ Wc) {
    int t = blockIdx.x * blockDim.x + threadIdx.x;
    if (t >= 4 * D * D) return;
    int j = t >> 7;
    int k = t & (D - 1);
    Wc[t] = W_ih[(size_t)j * (2 * D) + k] + W_hh[t];
}

// ---------------- b_sum = b_ih + b_hh; h1/c1 from biases only ----------------
__global__ void prep_bias_kernel(const float* __restrict__ b_ih, const float* __restrict__ b_hh,
                                 float* __restrict__ b_sum, float* __restrict__ h1,
                                 float* __restrict__ c1) {
    int t = threadIdx.x;  // 512 threads, 1 block
    float b = b_ih[t] + b_hh[t];
    b_sum[t] = b;
    if (t < D) {
        float bi = b_ih[t] + b_hh[t];
        float bg = b_ih[2 * D + t] + b_hh[2 * D + t];
        float bo = b_ih[3 * D + t] + b_hh[3 * D + t];
        float c = sigmoidf_(bi) * tanhf(bg);
        c1[t] = c;
        h1[t] = sigmoidf_(bo) * tanhf(c);
    }
}

// ---------------- base2[j] = b_sum[j] + dot(h1, Wc[j,:]) ----------------
__global__ void base2_kernel(const float* __restrict__ Wc, const float* __restrict__ b_sum,
                             const float* __restrict__ h1, float* __restrict__ base2) {
    __shared__ float hs[D];
    int j = blockIdx.x * 256 + threadIdx.x;
    if (threadIdx.x < D) hs[threadIdx.x] = h1[threadIdx.x];
    __syncthreads();
    float acc = 0.f;
    const float4* w4 = (const float4*)(Wc + (size_t)j * D);
#pragma unroll 8
    for (int k4 = 0; k4 < D / 4; ++k4) {
        float4 w = w4[k4];
        const float* hp = &hs[k4 * 4];
        acc += w.x * hp[0] + w.y * hp[1] + w.z * hp[2] + w.w * hp[3];
    }
    base2[j] = b_sum[j] + acc;
}

// ---------------- attention v3: single pass, 4 waves/segment, 8 rows per iteration ----
// Wave handles pairs: lanes 0-31 = even row, 32-63 = odd row, float4/lane.
// 4 pairs (4 KB) in flight per iteration (named regs); ONE online-softmax update per
// 8-row group (short serial chain). Per-wave (m,s,acc) merged through LDS at the end.
__global__ __launch_bounds__(256) void attn_kernel(
    const float* __restrict__ x,       // [N, D]
    const int* __restrict__ seg_off,   // [G+1]
    const float* __restrict__ q,       // [G, q_stride] or broadcast (stride 0)
    int q_stride,
    float* __restrict__ r_out, int r_stride,
    int G) {
    int g = blockIdx.x;
    if (g >= G) return;
    int tid = threadIdx.x;
    int wave = tid >> 6, lane = tid & 63;
    int half = lane >> 5, col4 = lane & 31;

    __shared__ float sm[4], ss[4];
    __shared__ float sacc[4][D];

    int start = seg_off[g], end = seg_off[g + 1];
    int count = end - start;
    int chunk = (count + 3) >> 2;
    int wsr = start + wave * chunk;
    int wer = min(wsr + chunk, end);

    const float4* x4 = (const float4*)x;   // row stride = 32 float4
    const float4* q4 = (const float4*)(q + (size_t)g * q_stride);
    float4 qv = q4[col4];

    float m = -INFINITY, s = 0.f;
    float4 acc = {0.f, 0.f, 0.f, 0.f};

    if (wsr < wer) {
        int last = wer - 1;
        int ngroups = (wer - wsr + 7) >> 3;
        for (int it = 0; it < ngroups; ++it) {
            int base = wsr + it * 8;
            int ra = min(base + 0 + half, last);
            int rb = min(base + 2 + half, last);
            int rc = min(base + 4 + half, last);
            int rd = min(base + 6 + half, last);
            float4 xa = x4[(size_t)ra * 32 + col4];
            float4 xb = x4[(size_t)rb * 32 + col4];
            float4 xc = x4[(size_t)rc * 32 + col4];
            float4 xd = x4[(size_t)rd * 32 + col4];

            float pa = xa.x * qv.x + xa.y * qv.y + xa.z * qv.z + xa.w * qv.w;
            float pb = xb.x * qv.x + xb.y * qv.y + xb.z * qv.z + xb.w * qv.w;
            float pc = xc.x * qv.x + xc.y * qv.y + xc.z * qv.z + xc.w * qv.w;
            float pd = xd.x * qv.x + xd.y * qv.y + xd.z * qv.z + xd.w * qv.w;
#pragma unroll
            for (int off = 1; off < 32; off <<= 1) {
                pa += __shfl_xor(pa, off);
                pb += __shfl_xor(pb, off);
                pc += __shfl_xor(pc, off);
                pd += __shfl_xor(pd, off);
            }
            float oa = __shfl_xor(pa, 32);
            float ob = __shfl_xor(pb, 32);
            float oc = __shfl_xor(pc, 32);
            float od = __shfl_xor(pd, 32);
            // even/odd row scores of each pair (all lanes)
            float pae = half ? oa : pa, pao = half ? pa : oa;
            float pbe = half ? ob : pb, pbo = half ? pb : ob;
            float pce = half ? oc : pc, pco = half ? pc : oc;
            float pde = half ? od : pd, pdo = half ? pd : od;
            // mask rows beyond the chunk
            pae = (base + 0 < wer) ? pae : -INFINITY;
            pao = (base + 1 < wer) ? pao : -INFINITY;
            pbe = (base + 2 < wer) ? pbe : -INFINITY;
            pbo = (base + 3 < wer) ? pbo : -INFINITY;
            pce = (base + 4 < wer) ? pce : -INFINITY;
            pco = (base + 5 < wer) ? pco : -INFINITY;
            pde = (base + 6 < wer) ? pde : -INFINITY;
            pdo = (base + 7 < wer) ? pdo : -INFINITY;

            float mn = fmaxf(fmaxf(fmaxf(pae, pao), fmaxf(pbe, pbo)),
                             fmaxf(fmaxf(pce, pco), fmaxf(pde, pdo)));
            mn = fmaxf(m, mn);
            float al = __expf(m - mn);   // first group: exp(-inf) = 0
            float wae = __expf(pae - mn), wao = __expf(pao - mn);
            float wbe = __expf(pbe - mn), wbo = __expf(pbo - mn);
            float wce = __expf(pce - mn), wco = __expf(pco - mn);
            float wde = __expf(pde - mn), wdo = __expf(pdo - mn);
            float sg = (wae + wao) + (wbe + wbo) + ((wce + wco) + (wde + wdo));
            s = s * al + sg;
            float wsa = half ? wao : wae;
            float wsb = half ? wbo : wbe;
            float wsc = half ? wco : wce;
            float wsd = half ? wdo : wde;
            float tx = wsa * xa.x + wsb * xb.x + wsc * xc.x + wsd * xd.x;
            float ty = wsa * xa.y + wsb * xb.y + wsc * xc.y + wsd * xd.y;
            float tz = wsa * xa.z + wsb * xb.z + wsc * xc.z + wsd * xd.z;
            float tw = wsa * xa.w + wsb * xb.w + wsc * xc.w + wsd * xd.w;
            acc.x = acc.x * al + tx;
            acc.y = acc.y * al + ty;
            acc.z = acc.z * al + tz;
            acc.w = acc.w * al + tw;
            m = mn;
        }
    }
    // merge the two 32-lane halves of this wave's accumulator
    acc.x += __shfl_xor(acc.x, 32);
    acc.y += __shfl_xor(acc.y, 32);
    acc.z += __shfl_xor(acc.z, 32);
    acc.w += __shfl_xor(acc.w, 32);

    if (lane == 0) { sm[wave] = m; ss[wave] = s; }
    if (half == 0) *(float4*)&sacc[wave][col4 * 4] = acc;
    __syncthreads();

    if (tid < D) {
        float m0 = sm[0], m1 = sm[1], m2 = sm[2], m3 = sm[3];
        float mstar = fmaxf(fmaxf(m0, m1), fmaxf(m2, m3));
        float r = 0.f;
        if (mstar > -INFINITY) {   // empty segment -> r = 0 (matches reference guard)
            float e0 = __expf(m0 - mstar), e1 = __expf(m1 - mstar);
            float e2 = __expf(m2 - mstar), e3 = __expf(m3 - mstar);
            float stot = ss[0] * e0 + ss[1] * e1 + ss[2] * e2 + ss[3] * e3;
            float at = sacc[0][tid] * e0 + sacc[1][tid] * e1
                     + sacc[2][tid] * e2 + sacc[3][tid] * e3;
            r = at / fmaxf(stot, 1e-16f);
        }
        r_out[(size_t)g * r_stride + tid] = r;
    }
}

// ---------------- gates GEMM (unchanged) ----------------
__global__ __launch_bounds__(256) void gates_gemm_kernel(
    const float* __restrict__ A1, const float* __restrict__ W1,
    const float* __restrict__ A2, const float* __restrict__ W2, int sW2,
    const float* __restrict__ bias, float* __restrict__ gates) {
    __shared__ float As[16][132];
    __shared__ float Ws[16][132];
    int t = threadIdx.x;
    int tx = t & 15, ty = t >> 4;
    int g0 = blockIdx.x * 128, j0 = blockIdx.y * 128;
    int lr = t >> 1;
    int lk = (t & 1) * 8;

    float acc[8][8];
#pragma unroll
    for (int i = 0; i < 8; ++i)
#pragma unroll
        for (int j = 0; j < 8; ++j) acc[i][j] = 0.f;

    for (int phase = 0; phase < 2; ++phase) {
        const float* A = phase ? A2 : A1;
        if (A == nullptr) continue;
        const float* W = phase ? W2 : W1;
        int sW = phase ? sW2 : D;
        for (int kk = 0; kk < D; kk += 16) {
            float4 a0 = *(const float4*)&A[(size_t)(g0 + lr) * D + kk + lk];
            float4 a1 = *(const float4*)&A[(size_t)(g0 + lr) * D + kk + lk + 4];
            float4 w0 = *(const float4*)&W[(size_t)(j0 + lr) * sW + kk + lk];
            float4 w1 = *(const float4*)&W[(size_t)(j0 + lr) * sW + kk + lk + 4];
            __syncthreads();
            As[lk + 0][lr] = a0.x; As[lk + 1][lr] = a0.y; As[lk + 2][lr] = a0.z; As[lk + 3][lr] = a0.w;
            As[lk + 4][lr] = a1.x; As[lk + 5][lr] = a1.y; As[lk + 6][lr] = a1.z; As[lk + 7][lr] = a1.w;
            Ws[lk + 0][lr] = w0.x; Ws[lk + 1][lr] = w0.y; Ws[lk + 2][lr] = w0.z; Ws[lk + 3][lr] = w0.w;
            Ws[lk + 4][lr] = w1.x; Ws[lk + 5][lr] = w1.y; Ws[lk + 6][lr] = w1.z; Ws[lk + 7][lr] = w1.w;
            __syncthreads();
#pragma unroll
            for (int k = 0; k < 16; ++k) {
                float4 a0v = *(const float4*)&As[k][ty * 8];
                float4 a1v = *(const float4*)&As[k][ty * 8 + 4];
                float4 b0v = *(const float4*)&Ws[k][tx * 8];
                float4 b1v = *(const float4*)&Ws[k][tx * 8 + 4];
                float av[8] = {a0v.x, a0v.y, a0v.z, a0v.w, a1v.x, a1v.y, a1v.z, a1v.w};
                float bv[8] = {b0v.x, b0v.y, b0v.z, b0v.w, b1v.x, b1v.y, b1v.z, b1v.w};
#pragma unroll
                for (int i = 0; i < 8; ++i)
#pragma unroll
                    for (int j = 0; j < 8; ++j)
                        acc[i][j] = fmaf(av[i], bv[j], acc[i][j]);
            }
        }
    }
#pragma unroll
    for (int i = 0; i < 8; ++i) {
        size_t row = (size_t)(g0 + ty * 8 + i);
        float4 o0, o1;
        int jb = j0 + tx * 8;
        o0.x = acc[i][0] + bias[jb + 0]; o0.y = acc[i][1] + bias[jb + 1];
        o0.z = acc[i][2] + bias[jb + 2]; o0.w = acc[i][3] + bias[jb + 3];
        o1.x = acc[i][4] + bias[jb + 4]; o1.y = acc[i][5] + bias[jb + 5];
        o1.z = acc[i][6] + bias[jb + 6]; o1.w = acc[i][7] + bias[jb + 7];
        *(float4*)&gates[row * 512 + jb] = o0;
        *(float4*)&gates[row * 512 + jb + 4] = o1;
    }
}

// ---------------- LSTM cell elementwise ----------------
__global__ void cell_kernel(const float* __restrict__ gates,
                            const float* __restrict__ c_prev, int c_stride,
                            float* __restrict__ c_out,
                            float* __restrict__ h_out, int h_stride,
                            int total) {
    int t = blockIdx.x * blockDim.x + threadIdx.x;
    if (t >= total) return;
    int g = t >> 7, k = t & (D - 1);
    const float* grow = gates + (size_t)g * 512;
    float ig = grow[k];
    float fg = grow[D + k];
    float gg = grow[2 * D + k];
    float og = grow[3 * D + k];
    float cp = c_prev[(size_t)g * c_stride + k];
    float c = sigmoidf_(fg) * cp + sigmoidf_(ig) * tanhf(gg);
    float h = sigmoidf_(og) * tanhf(c);
    c_out[t] = c;
    h_out[(size_t)g * h_stride + k] = h;
}

extern "C" void kernel_launch(void* const* d_in, const int* in_sizes, int n_in,
                              void* d_out, int out_size, void* d_ws, size_t ws_size,
                              hipStream_t stream) {
    const float* x      = (const float*)d_in[0];
    const float* W_ih   = (const float*)d_in[1];
    const float* W_hh   = (const float*)d_in[2];
    const float* b_ih   = (const float*)d_in[3];
    const float* b_hh   = (const float*)d_in[4];
    const int*   index  = (const int*)d_in[5];
    int N = in_sizes[5];
    int G = out_size / (2 * D);
    float* out = (float*)d_out;

    float* ws = (float*)d_ws;
    float* Wc     = ws;                         // 512*D
    float* b_sum  = Wc + 4 * D * D;             // 512
    float* h1     = b_sum + 4 * D;              // D
    float* c1     = h1 + D;                     // D
    float* base2  = c1 + D;                     // 512
    float* r1     = base2 + 4 * D;              // G*D
    float* h2     = r1 + (size_t)G * D;         // G*D
    float* c2     = h2 + (size_t)G * D;         // G*D
    float* r2     = c2 + (size_t)G * D;         // G*D
    float* gatesb = r2 + (size_t)G * D;         // G*4D
    int* seg_off  = (int*)(gatesb + (size_t)G * 4 * D);
    float* c3     = r1;  // r1 dead after step-3 GEMM; c3 never read

    seg_bounds_kernel<<<(G + 1 + 255) / 256, 256, 0, stream>>>(index, N, G, seg_off);
    prep_wc_kernel<<<(4 * D * D + 255) / 256, 256, 0, stream>>>(W_ih, W_hh, Wc);
    prep_bias_kernel<<<1, 512, 0, stream>>>(b_ih, b_hh, b_sum, h1, c1);
    base2_kernel<<<2, 256, 0, stream>>>(Wc, b_sum, h1, base2);

    // ---- step 1: q = h1 (broadcast)
    attn_kernel<<<G, 256, 0, stream>>>(x, seg_off, h1, 0, r1, D, G);

    // ---- step 2
    gates_gemm_kernel<<<dim3(G / 128, 4), 256, 0, stream>>>(
        nullptr, Wc, r1, W_ih + D, 2 * D, base2, gatesb);
    cell_kernel<<<(G * D + 255) / 256, 256, 0, stream>>>(gatesb, c1, 0, c2, h2, D, G * D);
    attn_kernel<<<G, 256, 0, stream>>>(x, seg_off, h2, D, r2, D, G);

    // ---- step 3
    gates_gemm_kernel<<<dim3(G / 128, 4), 256, 0, stream>>>(
        h2, Wc, r2, W_ih + D, 2 * D, b_sum, gatesb);
    cell_kernel<<<(G * D + 255) / 256, 256, 0, stream>>>(gatesb, c2, D, c3, out, 2 * D, G * D);
    attn_kernel<<<G, 256, 0, stream>>>(x, seg_off, out, 2 * D, out + D, 2 * D, G);
}

// Round 6
// 494.581 us; speedup vs baseline: 1.5445x; 1.0578x over previous
//
#include <hip/hip_runtime.h>
#include <math.h>

#define D 128

__device__ __forceinline__ float sigmoidf_(float x) { return 1.f / (1.f + __expf(-x)); }

// ---------------- fused prep: Wc | seg_off | b_sum,h1,c1  (partitioned by blockIdx) ----
// blocks [0,256): Wc = W_ih[:, :D] + W_hh          (65536 elements)
// blocks [256,273): seg_off[g] = lower_bound(index, g), g in [0, G]
// block 273: b_sum = b_ih + b_hh; h1/c1 from biases only (step-1 LSTM is constant: q*=h=c=0)
__global__ void prep_kernel(const float* __restrict__ W_ih, const float* __restrict__ W_hh,
                            const float* __restrict__ b_ih, const float* __restrict__ b_hh,
                            const int* __restrict__ idx, int N, int G,
                            float* __restrict__ Wc, int* __restrict__ seg_off,
                            float* __restrict__ b_sum, float* __restrict__ h1,
                            float* __restrict__ c1) {
    int b = blockIdx.x, t = threadIdx.x;
    if (b < 256) {
        int i = b * 256 + t;              // 0..65535
        int j = i >> 7, k = i & (D - 1);
        Wc[i] = W_ih[(size_t)j * (2 * D) + k] + W_hh[i];
    } else if (b < 273) {
        int g = (b - 256) * 256 + t;
        if (g <= G) {
            int lo = 0, hi = N;
            while (lo < hi) {
                int mid = (lo + hi) >> 1;
                if (idx[mid] < g) lo = mid + 1; else hi = mid;
            }
            seg_off[g] = lo;
        }
    } else {
        for (int i = t; i < 4 * D; i += 256) b_sum[i] = b_ih[i] + b_hh[i];
        if (t < D) {
            float bi = b_ih[t] + b_hh[t];
            float bg = b_ih[2 * D + t] + b_hh[2 * D + t];
            float bo = b_ih[3 * D + t] + b_hh[3 * D + t];
            float c = sigmoidf_(bi) * tanhf(bg);   // c0 = 0 -> f-gate term vanishes
            c1[t] = c;
            h1[t] = sigmoidf_(bo) * tanhf(c);
        }
    }
}

// ---------------- attention: single pass, 4 waves/segment, 8 rows per iteration ----
// (unchanged from R5 — runs near streaming rate)
__global__ __launch_bounds__(256) void attn_kernel(
    const float* __restrict__ x, const int* __restrict__ seg_off,
    const float* __restrict__ q, int q_stride,
    float* __restrict__ r_out, int r_stride, int G) {
    int g = blockIdx.x;
    if (g >= G) return;
    int tid = threadIdx.x;
    int wave = tid >> 6, lane = tid & 63;
    int half = lane >> 5, col4 = lane & 31;

    __shared__ float sm[4], ss[4];
    __shared__ float sacc[4][D];

    int start = seg_off[g], end = seg_off[g + 1];
    int count = end - start;
    int chunk = (count + 3) >> 2;
    int wsr = start + wave * chunk;
    int wer = min(wsr + chunk, end);

    const float4* x4 = (const float4*)x;
    const float4* q4 = (const float4*)(q + (size_t)g * q_stride);
    float4 qv = q4[col4];

    float m = -INFINITY, s = 0.f;
    float4 acc = {0.f, 0.f, 0.f, 0.f};

    if (wsr < wer) {
        int last = wer - 1;
        int ngroups = (wer - wsr + 7) >> 3;
        for (int it = 0; it < ngroups; ++it) {
            int base = wsr + it * 8;
            int ra = min(base + 0 + half, last);
            int rb = min(base + 2 + half, last);
            int rc = min(base + 4 + half, last);
            int rd = min(base + 6 + half, last);
            float4 xa = x4[(size_t)ra * 32 + col4];
            float4 xb = x4[(size_t)rb * 32 + col4];
            float4 xc = x4[(size_t)rc * 32 + col4];
            float4 xd = x4[(size_t)rd * 32 + col4];

            float pa = xa.x * qv.x + xa.y * qv.y + xa.z * qv.z + xa.w * qv.w;
            float pb = xb.x * qv.x + xb.y * qv.y + xb.z * qv.z + xb.w * qv.w;
            float pc = xc.x * qv.x + xc.y * qv.y + xc.z * qv.z + xc.w * qv.w;
            float pd = xd.x * qv.x + xd.y * qv.y + xd.z * qv.z + xd.w * qv.w;
#pragma unroll
            for (int off = 1; off < 32; off <<= 1) {
                pa += __shfl_xor(pa, off);
                pb += __shfl_xor(pb, off);
                pc += __shfl_xor(pc, off);
                pd += __shfl_xor(pd, off);
            }
            float oa = __shfl_xor(pa, 32);
            float ob = __shfl_xor(pb, 32);
            float oc = __shfl_xor(pc, 32);
            float od = __shfl_xor(pd, 32);
            float pae = half ? oa : pa, pao = half ? pa : oa;
            float pbe = half ? ob : pb, pbo = half ? pb : ob;
            float pce = half ? oc : pc, pco = half ? pc : oc;
            float pde = half ? od : pd, pdo = half ? pd : od;
            pae = (base + 0 < wer) ? pae : -INFINITY;
            pao = (base + 1 < wer) ? pao : -INFINITY;
            pbe = (base + 2 < wer) ? pbe : -INFINITY;
            pbo = (base + 3 < wer) ? pbo : -INFINITY;
            pce = (base + 4 < wer) ? pce : -INFINITY;
            pco = (base + 5 < wer) ? pco : -INFINITY;
            pde = (base + 6 < wer) ? pde : -INFINITY;
            pdo = (base + 7 < wer) ? pdo : -INFINITY;

            float mn = fmaxf(fmaxf(fmaxf(pae, pao), fmaxf(pbe, pbo)),
                             fmaxf(fmaxf(pce, pco), fmaxf(pde, pdo)));
            mn = fmaxf(m, mn);
            float al = __expf(m - mn);
            float wae = __expf(pae - mn), wao = __expf(pao - mn);
            float wbe = __expf(pbe - mn), wbo = __expf(pbo - mn);
            float wce = __expf(pce - mn), wco = __expf(pco - mn);
            float wde = __expf(pde - mn), wdo = __expf(pdo - mn);
            float sg = (wae + wao) + (wbe + wbo) + ((wce + wco) + (wde + wdo));
            s = s * al + sg;
            float wsa = half ? wao : wae;
            float wsb = half ? wbo : wbe;
            float wsc = half ? wco : wce;
            float wsd = half ? wdo : wde;
            float tx = wsa * xa.x + wsb * xb.x + wsc * xc.x + wsd * xd.x;
            float ty = wsa * xa.y + wsb * xb.y + wsc * xc.y + wsd * xd.y;
            float tz = wsa * xa.z + wsb * xb.z + wsc * xc.z + wsd * xd.z;
            float tw = wsa * xa.w + wsb * xb.w + wsc * xc.w + wsd * xd.w;
            acc.x = acc.x * al + tx;
            acc.y = acc.y * al + ty;
            acc.z = acc.z * al + tz;
            acc.w = acc.w * al + tw;
            m = mn;
        }
    }
    acc.x += __shfl_xor(acc.x, 32);
    acc.y += __shfl_xor(acc.y, 32);
    acc.z += __shfl_xor(acc.z, 32);
    acc.w += __shfl_xor(acc.w, 32);

    if (lane == 0) { sm[wave] = m; ss[wave] = s; }
    if (half == 0) *(float4*)&sacc[wave][col4 * 4] = acc;
    __syncthreads();

    if (tid < D) {
        float m0 = sm[0], m1 = sm[1], m2 = sm[2], m3 = sm[3];
        float mstar = fmaxf(fmaxf(m0, m1), fmaxf(m2, m3));
        float r = 0.f;
        if (mstar > -INFINITY) {
            float e0 = __expf(m0 - mstar), e1 = __expf(m1 - mstar);
            float e2 = __expf(m2 - mstar), e3 = __expf(m3 - mstar);
            float stot = ss[0] * e0 + ss[1] * e1 + ss[2] * e2 + ss[3] * e3;
            float at = sacc[0][tid] * e0 + sacc[1][tid] * e1
                     + sacc[2][tid] * e2 + sacc[3][tid] * e3;
            r = at / fmaxf(stot, 1e-16f);
        }
        r_out[(size_t)g * r_stride + tid] = r;
    }
}

// ---------------- gates GEMM v2: 64x64 tile, 4x4 micro-tile, KC=32, 512 blocks ------
// gates[g,j] = bias[j] + A1[g·sA1, :]·W1[j,:] + A2[g,:]·W2[j·sW2, :]
// sA1=0 expresses a broadcast row (step-2's constant h1 term — replaces base2).
__global__ __launch_bounds__(256) void gates_gemm_kernel(
    const float* __restrict__ A1, int sA1,
    const float* __restrict__ W1,                  // [512, D] stride D (Wc)
    const float* __restrict__ A2,                  // [G, D] stride D
    const float* __restrict__ W2, int sW2,         // W_ih + D, stride 2D
    const float* __restrict__ bias,                // [512] (b_sum)
    float* __restrict__ gates) {                   // [G, 512]
    __shared__ float As[32][72];
    __shared__ float Ws[32][72];
    int t = threadIdx.x;
    int tx = t & 15, ty = t >> 4;
    int g0 = blockIdx.x * 64, j0 = blockIdx.y * 64;
    int lr = t & 63;            // row this thread stages
    int lk = (t >> 6) * 8;      // k-offset this thread stages (0,8,16,24)

    float acc[4][4];
#pragma unroll
    for (int i = 0; i < 4; ++i)
#pragma unroll
        for (int j = 0; j < 4; ++j) acc[i][j] = 0.f;

    for (int phase = 0; phase < 2; ++phase) {
        const float* A = phase ? A2 : A1;
        int sA = phase ? D : sA1;
        const float* W = phase ? W2 : W1;
        int sW = phase ? sW2 : D;
        for (int kk = 0; kk < D; kk += 32) {
            float4 a0 = *(const float4*)&A[(size_t)(g0 + lr) * sA + kk + lk];
            float4 a1 = *(const float4*)&A[(size_t)(g0 + lr) * sA + kk + lk + 4];
            float4 w0 = *(const float4*)&W[(size_t)(j0 + lr) * sW + kk + lk];
            float4 w1 = *(const float4*)&W[(size_t)(j0 + lr) * sW + kk + lk + 4];
            __syncthreads();
            As[lk + 0][lr] = a0.x; As[lk + 1][lr] = a0.y; As[lk + 2][lr] = a0.z; As[lk + 3][lr] = a0.w;
            As[lk + 4][lr] = a1.x; As[lk + 5][lr] = a1.y; As[lk + 6][lr] = a1.z; As[lk + 7][lr] = a1.w;
            Ws[lk + 0][lr] = w0.x; Ws[lk + 1][lr] = w0.y; Ws[lk + 2][lr] = w0.z; Ws[lk + 3][lr] = w0.w;
            Ws[lk + 4][lr] = w1.x; Ws[lk + 5][lr] = w1.y; Ws[lk + 6][lr] = w1.z; Ws[lk + 7][lr] = w1.w;
            __syncthreads();
#pragma unroll
            for (int k = 0; k < 32; ++k) {
                float4 av = *(const float4*)&As[k][ty * 4];
                float4 bv = *(const float4*)&Ws[k][tx * 4];
                float aa[4] = {av.x, av.y, av.z, av.w};
                float bb[4] = {bv.x, bv.y, bv.z, bv.w};
#pragma unroll
                for (int i = 0; i < 4; ++i)
#pragma unroll
                    for (int j = 0; j < 4; ++j)
                        acc[i][j] = fmaf(aa[i], bb[j], acc[i][j]);
            }
        }
    }
#pragma unroll
    for (int i = 0; i < 4; ++i) {
        size_t row = (size_t)(g0 + ty * 4 + i);
        int jb = j0 + tx * 4;
        float4 o;
        o.x = acc[i][0] + bias[jb + 0];
        o.y = acc[i][1] + bias[jb + 1];
        o.z = acc[i][2] + bias[jb + 2];
        o.w = acc[i][3] + bias[jb + 3];
        *(float4*)&gates[row * 512 + jb] = o;
    }
}

// ---------------- LSTM cell elementwise ----------------
__global__ void cell_kernel(const float* __restrict__ gates,
                            const float* __restrict__ c_prev, int c_stride,
                            float* __restrict__ c_out,
                            float* __restrict__ h_out, int h_stride,
                            int total) {
    int t = blockIdx.x * blockDim.x + threadIdx.x;
    if (t >= total) return;
    int g = t >> 7, k = t & (D - 1);
    const float* grow = gates + (size_t)g * 512;
    float ig = grow[k];
    float fg = grow[D + k];
    float gg = grow[2 * D + k];
    float og = grow[3 * D + k];
    float cp = c_prev[(size_t)g * c_stride + k];
    float c = sigmoidf_(fg) * cp + sigmoidf_(ig) * tanhf(gg);
    float h = sigmoidf_(og) * tanhf(c);
    c_out[t] = c;
    h_out[(size_t)g * h_stride + k] = h;
}

extern "C" void kernel_launch(void* const* d_in, const int* in_sizes, int n_in,
                              void* d_out, int out_size, void* d_ws, size_t ws_size,
                              hipStream_t stream) {
    const float* x      = (const float*)d_in[0];
    const float* W_ih   = (const float*)d_in[1];
    const float* W_hh   = (const float*)d_in[2];
    const float* b_ih   = (const float*)d_in[3];
    const float* b_hh   = (const float*)d_in[4];
    const int*   index  = (const int*)d_in[5];
    int N = in_sizes[5];
    int G = out_size / (2 * D);
    float* out = (float*)d_out;

    float* ws = (float*)d_ws;
    float* Wc     = ws;                         // 512*D
    float* b_sum  = Wc + 4 * D * D;             // 512
    float* h1     = b_sum + 4 * D;              // D
    float* c1     = h1 + D;                     // D
    float* r1     = c1 + D;                     // G*D
    float* h2     = r1 + (size_t)G * D;         // G*D
    float* c2     = h2 + (size_t)G * D;         // G*D
    float* r2     = c2 + (size_t)G * D;         // G*D
    float* gatesb = r2 + (size_t)G * D;         // G*4D
    int* seg_off  = (int*)(gatesb + (size_t)G * 4 * D);
    float* c3     = r1;  // r1 dead after step-3 GEMM; c3 never read

    // ---- fused prep (Wc | seg_off | b_sum,h1,c1)
    prep_kernel<<<274, 256, 0, stream>>>(W_ih, W_hh, b_ih, b_hh, index, N, G,
                                         Wc, seg_off, b_sum, h1, c1);

    // ---- step 1: attention with broadcast q = h1
    attn_kernel<<<G, 256, 0, stream>>>(x, seg_off, h1, 0, r1, D, G);

    // ---- step 2: gates = b_sum + h1(bcast)@Wc^T + r1@Wr^T
    gates_gemm_kernel<<<dim3(G / 64, 8), 256, 0, stream>>>(
        h1, 0, Wc, r1, W_ih + D, 2 * D, b_sum, gatesb);
    cell_kernel<<<(G * D + 255) / 256, 256, 0, stream>>>(gatesb, c1, 0, c2, h2, D, G * D);
    attn_kernel<<<G, 256, 0, stream>>>(x, seg_off, h2, D, r2, D, G);

    // ---- step 3: gates = b_sum + h2@Wc^T + r2@Wr^T ; h3 -> out[:, :D]
    gates_gemm_kernel<<<dim3(G / 64, 8), 256, 0, stream>>>(
        h2, D, Wc, r2, W_ih + D, 2 * D, b_sum, gatesb);
    cell_kernel<<<(G * D + 255) / 256, 256, 0, stream>>>(gatesb, c2, D, c3, out, 2 * D, G * D);
    attn_kernel<<<G, 256, 0, stream>>>(x, seg_off, out, 2 * D, out + D, 2 * D, G);
}